// Round 6
// baseline (306.374 us; speedup 1.0000x reference)
//
#include <hip/hip_runtime.h>
#include <hip/hip_bf16.h>
#include <stdint.h>

#define NROWS   65536
#define OUTW    2193
#define N3      1224
#define H2N     100
#define TAILN   969
#define NUNITS  100      // 39 main units (2 tiles each) + 61 pair units
#define NCOLG   25       // 4 units (waves) per block
#define NSTRIP  128
#define RSTRIP  512      // rows per strip
#define CHUNKS  32       // 16-row chunks per strip
#define NCHUNKT 4096     // total chunks

typedef __attribute__((ext_vector_type(8))) short bf16x8;
typedef __attribute__((ext_vector_type(4))) float f32x4;

// ws layout (bytes)
#define H2F_OFF  0u
#define H2F_SZ   16777216u          // 4096 chunks * 4KB
#define W3F_OFF  16777216u
#define W3F_SZ   819200u            // 200 sides * 4 ks * 64 * 8 bf16
#define B3U_OFF  (W3F_OFF + W3F_SZ)             // 200*16 f32 = 12800
#define PWU_OFF  (B3U_OFF + 12800u)             // 61*16 f32  = 3904
#define W2F_OFF  (PWU_OFF + 3904u)              // 7*64*8 bf16 = 7168
#define B2P_OFF  (W2F_OFF + 7168u)              // 112 f32    = 448

__device__ __forceinline__ float fast_sigmoid(float z){
    return __builtin_amdgcn_rcpf(1.0f + __expf(-z));
}
__device__ __forceinline__ unsigned short f2bf(float v){
    __hip_bfloat16 h = __float2bfloat16(v);
    return *reinterpret_cast<unsigned short*>(&h);
}
__device__ __forceinline__ void store16(float* p, f32x4 v){
    __builtin_memcpy(p, &v, 16);
}

// ---------------- prep: W3 -> w3f (200 sides, unit order), b3u, pwu, W2 -> w2f, b2p
__global__ void prep_kernel(const float* __restrict__ W3, const float* __restrict__ b3,
                            const float* __restrict__ wgt,
                            const int* __restrict__ idx1, const int* __restrict__ idx2,
                            const float* __restrict__ W2, const float* __restrict__ b2,
                            unsigned short* __restrict__ w3f, float* __restrict__ b3u,
                            float* __restrict__ pwu,
                            unsigned short* __restrict__ w2f, float* __restrict__ b2p)
{
    const int blk = blockIdx.x, tid = threadIdx.x;
    const int ks = tid >> 6, lane = tid & 63;
    const int lm = lane & 15, lgf = lane >> 4;

    if (blk < 200){
        const int u = blk >> 1, s = blk & 1;
        int col = -1;
        if (u < 39){
            int t = u * 2 + s;              // t==77 stays pad
            int c = t * 16 + lm;
            if (t < 77 && c < N3) col = c;
        } else {
            int p = u - 39, pos = p * 16 + lm;
            if (pos < TAILN){
                int j = pos / 17;
                col = (s ? idx2[j] : idx1[j]) * 17 + (pos - j * 17);
            }
        }
        unsigned short vals[8];
        #pragma unroll
        for (int e = 0; e < 8; ++e){
            int k = ks * 32 + lgf * 8 + e;
            float v = (col >= 0 && k < H2N) ? W3[k * N3 + col] : 0.0f;
            vals[e] = f2bf(v);
        }
        *reinterpret_cast<bf16x8*>(w3f + ((size_t)(blk * 4 + ks) * 64 + lane) * 8)
            = *reinterpret_cast<bf16x8*>(vals);

        if (ks == 0 && lgf == 0) b3u[blk * 16 + lm] = (col >= 0) ? b3[col] : 0.0f;
        if (ks == 0 && lgf == 1 && u >= 39 && s == 0){
            int p = u - 39, pos = p * 16 + lm;
            pwu[p * 16 + lm] = (pos < TAILN) ? wgt[pos / 17] : 0.0f;
        }
    } else if (blk < 207 && ks == 0){
        const int t = blk - 200;            // W2 tile 0..6
        int c = t * 16 + lm;
        unsigned short vals[8];
        #pragma unroll
        for (int e = 0; e < 8; ++e){
            int k = lgf * 8 + e;
            float v = (k < 10 && c < H2N) ? W2[k * H2N + c] : 0.0f;
            vals[e] = f2bf(v);
        }
        *reinterpret_cast<bf16x8*>(w2f + ((size_t)t * 64 + lane) * 8)
            = *reinterpret_cast<bf16x8*>(vals);
        if (lgf == 0) b2p[t * 16 + lm] = (c < H2N) ? b2[c] : 0.0f;
    }
}

// ---------------- h2f: layers 1+2 via MFMA, output fragment-ordered bf16 h2
__global__ __launch_bounds__(256)
void h2f_kernel(const float* __restrict__ x,
                const float* __restrict__ W1, const float* __restrict__ b1,
                const unsigned short* __restrict__ w2f, const float* __restrict__ b2p,
                unsigned short* __restrict__ h2f)
{
    __shared__ unsigned short hl[4][16][128];   // per-wave 16x128 bf16, 16 KB total
    const int tid = threadIdx.x, lane = tid & 63, wid = tid >> 6;
    const int lm = lane & 15, lgf = lane >> 4;
    const int chunk = blockIdx.x * 4 + wid;
    const int row = chunk * 16 + lm;

    // h1 fragment (B operand): k = lgf*8+e, real for k<10
    const float xv = x[row];
    unsigned short hv[8];
    #pragma unroll
    for (int e = 0; e < 8; ++e){
        int j = lgf * 8 + e;
        float v = 0.0f;
        if (j < 10) v = fast_sigmoid(xv * W1[j] + b1[j]);
        hv[e] = f2bf(v);
    }
    bf16x8 hfrag = *reinterpret_cast<bf16x8*>(hv);

    char* lbase = (char*)&hl[wid][0][0];
    #pragma unroll
    for (int t = 0; t < 7; ++t){
        bf16x8 wfr = *reinterpret_cast<const bf16x8*>(w2f + ((size_t)t * 64 + lane) * 8);
        f32x4 acc = {0,0,0,0};
        acc = __builtin_amdgcn_mfma_f32_16x16x32_bf16(wfr, hfrag, acc, 0, 0, 0);
        const f32x4 bv = *reinterpret_cast<const f32x4*>(b2p + t * 16 + lgf * 4);
        unsigned short o[4];
        #pragma unroll
        for (int r = 0; r < 4; ++r){
            int c = t * 16 + lgf * 4 + r;
            o[r] = (c < H2N) ? f2bf(fast_sigmoid(acc[r] + bv[r])) : 0;
        }
        int byte = lm * 256 + (t * 16 + lgf * 4) * 2;
        byte ^= (lm & 7) << 4;                    // bank swizzle
        __builtin_memcpy(lbase + byte, o, 8);
    }
    {   // zero cols 112..127 (avoid NaN garbage; w3f k>=100 is zero so value is moot)
        unsigned short z[4] = {0,0,0,0};
        int byte = lm * 256 + (112 + lgf * 4) * 2;
        byte ^= (lm & 7) << 4;
        __builtin_memcpy(lbase + byte, z, 8);
    }
    __syncthreads();

    unsigned short* gb = h2f + (size_t)chunk * 2048 + lane * 8;
    #pragma unroll
    for (int ks = 0; ks < 4; ++ks){
        int byte = lm * 256 + ks * 64 + lgf * 16;
        byte ^= (lm & 7) << 4;
        bf16x8 v;
        __builtin_memcpy(&v, lbase + byte, 16);
        *reinterpret_cast<bf16x8*>(gb + ks * 512) = v;
    }
}

// ---------------- gemm: W3 register-resident, stream h2 chunks
__global__ __launch_bounds__(256, 4)
void gemm_kernel(const unsigned short* __restrict__ h2f,
                 const unsigned short* __restrict__ w3f,
                 const float* __restrict__ b3u, const float* __restrict__ pwu,
                 float* __restrict__ out)
{
    const int tid = threadIdx.x, lane = tid & 63, wid = tid >> 6;
    const int lm = lane & 15, lg = lane >> 4;
    const int colg  = blockIdx.x % NCOLG;
    const int strip = blockIdx.x / NCOLG;
    const int u = colg * 4 + wid;                 // 0..99
    const int s0 = u * 2, s1 = s0 + 1;

    // W3 fragments: resident for the whole block
    bf16x8 wf0[4], wf1[4];
    #pragma unroll
    for (int ks = 0; ks < 4; ++ks){
        wf0[ks] = *reinterpret_cast<const bf16x8*>(w3f + ((size_t)(s0 * 4 + ks) * 64 + lane) * 8);
        wf1[ks] = *reinterpret_cast<const bf16x8*>(w3f + ((size_t)(s1 * 4 + ks) * 64 + lane) * 8);
    }
    const f32x4 bv0 = *reinterpret_cast<const f32x4*>(b3u + s0 * 16 + lg * 4);
    const f32x4 bv1 = *reinterpret_cast<const f32x4*>(b3u + s1 * 16 + lg * 4);
    const bool isPair = (u >= 39);
    f32x4 wv = {0,0,0,0};
    int colA, colB = 0;
    if (!isPair){ colA = u * 32 + lg * 4; colB = colA + 16; }
    else {
        const int p = u - 39;
        colA = N3 + p * 16 + lg * 4;
        wv = *reinterpret_cast<const f32x4*>(pwu + p * 16 + lg * 4);
    }

    unsigned int rowoff = (unsigned int)(strip * RSTRIP + lm) * OUTW;
    const char* hbase = (const char*)h2f + (size_t)strip * CHUNKS * 4096 + lane * 16;

    bf16x8 hc[4], hn[4];
    #pragma unroll
    for (int ks = 0; ks < 4; ++ks)
        hc[ks] = *reinterpret_cast<const bf16x8*>(hbase + ks * 1024);

    for (int c = 0; c < CHUNKS; ++c){
        if (c + 1 < CHUNKS){
            const char* hp = hbase + (size_t)(c + 1) * 4096;
            #pragma unroll
            for (int ks = 0; ks < 4; ++ks)
                hn[ks] = *reinterpret_cast<const bf16x8*>(hp + ks * 1024);
        }

        f32x4 a0 = {0,0,0,0}, a1 = {0,0,0,0};
        #pragma unroll
        for (int ks = 0; ks < 4; ++ks){
            a0 = __builtin_amdgcn_mfma_f32_16x16x32_bf16(wf0[ks], hc[ks], a0, 0, 0, 0);
            a1 = __builtin_amdgcn_mfma_f32_16x16x32_bf16(wf1[ks], hc[ks], a1, 0, 0, 0);
        }

        if (u < 38){                               // both main tiles full
            f32x4 v0, v1;
            #pragma unroll
            for (int r = 0; r < 4; ++r){
                v0[r] = fast_sigmoid(a0[r] + bv0[r]);
                v1[r] = fast_sigmoid(a1[r] + bv1[r]);
            }
            store16(out + rowoff + colA, v0);
            store16(out + rowoff + colB, v1);
        } else if (u == 38){                       // tile 76: cols 1216..1223 only
            f32x4 v0;
            #pragma unroll
            for (int r = 0; r < 4; ++r) v0[r] = fast_sigmoid(a0[r] + bv0[r]);
            if (lg < 2) store16(out + rowoff + colA, v0);
        } else {                                   // pair units
            f32x4 v;
            #pragma unroll
            for (int r = 0; r < 4; ++r){
                float u1 = fast_sigmoid(a0[r] + bv0[r]);
                float u2 = fast_sigmoid(a1[r] + bv1[r]);
                v[r] = fmaf(wv[r], u1 - u2, u2);
            }
            if (u < 99)      store16(out + rowoff + colA, v);
            else {                                 // p=60: 9 valid outputs
                if (lg < 2)       store16(out + rowoff + colA, v);
                else if (lg == 2) out[rowoff + colA] = v[0];
            }
        }

        rowoff += 16u * OUTW;
        if (c + 1 < CHUNKS){
            #pragma unroll
            for (int ks = 0; ks < 4; ++ks) hc[ks] = hn[ks];
        }
    }
}

extern "C" void kernel_launch(void* const* d_in, const int* in_sizes, int n_in,
                              void* d_out, int out_size, void* d_ws, size_t ws_size,
                              hipStream_t stream)
{
    const float* x   = (const float*)d_in[0];
    const float* W1  = (const float*)d_in[1];
    const float* b1  = (const float*)d_in[2];
    const float* W2  = (const float*)d_in[3];
    const float* b2  = (const float*)d_in[4];
    const float* W3  = (const float*)d_in[5];
    const float* b3  = (const float*)d_in[6];
    const float* wgt = (const float*)d_in[7];
    const int*   i1  = (const int*)d_in[8];
    const int*   i2  = (const int*)d_in[9];
    float* out = (float*)d_out;

    unsigned char* ws = (unsigned char*)d_ws;
    unsigned short* h2f = (unsigned short*)(ws + H2F_OFF);
    unsigned short* w3f = (unsigned short*)(ws + W3F_OFF);
    float*          b3u = (float*)(ws + B3U_OFF);
    float*          pwu = (float*)(ws + PWU_OFF);
    unsigned short* w2f = (unsigned short*)(ws + W2F_OFF);
    float*          b2p = (float*)(ws + B2P_OFF);

    prep_kernel<<<207, 256, 0, stream>>>(W3, b3, wgt, i1, i2, W2, b2,
                                         w3f, b3u, pwu, w2f, b2p);
    h2f_kernel<<<NCHUNKT / 4, 256, 0, stream>>>(x, W1, b1, w2f, b2p, h2f);
    gemm_kernel<<<NCOLG * NSTRIP, 256, 0, stream>>>(h2f, w3f, b3u, pwu, out);
}

// Round 7
// 240.992 us; speedup vs baseline: 1.2713x; 1.2713x over previous
//
#include <hip/hip_runtime.h>
#include <hip/hip_bf16.h>
#include <stdint.h>

#define NROWS   65536
#define RPB     32
#define NBLK    (NROWS/RPB)       // 2048
#define H2N     100
#define KPAD    128
#define N3      1224
#define OUTW    2193
#define TAILN   969
#define NTILE   138               // logical tiles: 77 main + 61 pair
#define T1OFF   77
#define T2OFF   138
#define NTOT    199               // frag tiles in w3f
#define VWIDTH  2208              // virtual: 1232 main-padded + 976 tail-padded
#define PANELW  256               // virtual cols per panel (16 tiles)
#define NPANEL  9
#define PSTR    268               // f32 row stride of LDS panel (16B-aligned, balanced banks)

typedef __attribute__((ext_vector_type(8))) short bf16x8;
typedef __attribute__((ext_vector_type(4))) float f32x4;

__device__ __forceinline__ float fast_sigmoid(float z){
    return __builtin_amdgcn_rcpf(1.0f + __expf(-z));
}
__device__ __forceinline__ unsigned short f2bf(float v){
    __hip_bfloat16 h = __float2bfloat16(v);
    return *reinterpret_cast<unsigned short*>(&h);
}
__device__ __forceinline__ void store16(float* p, f32x4 v){
    __builtin_memcpy(p, &v, 16);
}

// Build fragment-ordered extended B: w3f[((t*4+ks)*64+lane)*8 + e]
//   = bf16( W3[k=ks*32+(lane>>4)*8+e][ srccol(t, lane&15) ] ), zero-padded.
// frag tiles: 0..76 main cols; 77..137 gathered c1; 138..198 gathered c2.
__global__ void prep_kernel(const float* __restrict__ W3,
                            const float* __restrict__ b3,
                            const float* __restrict__ wgt,
                            const int* __restrict__ idx1,
                            const int* __restrict__ idx2,
                            unsigned short* __restrict__ w3f,
                            float* __restrict__ b3f,
                            float* __restrict__ pwf){
    const int t    = blockIdx.x;            // one frag tile per block
    const int ks   = threadIdx.x >> 6;
    const int lane = threadIdx.x & 63;
    const int lm   = lane & 15, lgf = lane >> 4;

    int col = -1;
    if (t < T1OFF){
        int c = t * 16 + lm;
        if (c < N3) col = c;
    } else if (t < T2OFF){
        int p = (t - T1OFF) * 16 + lm;
        if (p < TAILN){ int j = p / 17; col = idx1[j] * 17 + (p - j * 17); }
    } else {
        int p = (t - T2OFF) * 16 + lm;
        if (p < TAILN){ int j = p / 17; col = idx2[j] * 17 + (p - j * 17); }
    }

    unsigned short vals[8];
    #pragma unroll
    for (int e = 0; e < 8; ++e){
        int k = ks * 32 + lgf * 8 + e;
        float v = (col >= 0 && k < H2N) ? W3[k * N3 + col] : 0.0f;
        vals[e] = f2bf(v);
    }
    *reinterpret_cast<bf16x8*>(w3f + ((size_t)(t * 4 + ks) * 64 + lane) * 8)
        = *reinterpret_cast<bf16x8*>(vals);

    if (ks == 0 && lgf == 0)
        b3f[t * 16 + lm] = (col >= 0) ? b3[col] : 0.0f;
    if (ks == 0 && lgf == 1 && t >= T1OFF && t < T2OFF){
        int p = (t - T1OFF) * 16 + lm;
        if (p < TAILN) pwf[p] = wgt[p / 17];
    }
}

__global__ __launch_bounds__(256, 3)
void snn_kernel(const float* __restrict__ x,
                const float* __restrict__ W1, const float* __restrict__ b1,
                const float* __restrict__ W2, const float* __restrict__ b2,
                const unsigned short* __restrict__ w3f,
                const float* __restrict__ b3f,
                const float* __restrict__ pwf,
                float* __restrict__ out)
{
    __shared__ __align__(16) unsigned short lds_h2[RPB][KPAD];   // 8 KB
    __shared__ float lds_h1[RPB][10];
    __shared__ __align__(16) float lds_p[RPB][PSTR];             // 33.5 KB panel

    const int t    = threadIdx.x;
    const int row0 = blockIdx.x * RPB;

    // ---- layer 1
    for (int i = t; i < RPB * 10; i += 256){
        int r = i / 10, j = i - r * 10;
        lds_h1[r][j] = fast_sigmoid(x[row0 + r] * W1[j] + b1[j]);
    }
    __syncthreads();

    // ---- layer 2 -> bf16 LDS (k 100..127 zero-padded)
    for (int i = t; i < RPB * KPAD; i += 256){
        int r = i >> 7, c = i & 127;
        float v = 0.0f;
        if (c < H2N){
            float z = b2[c];
            #pragma unroll
            for (int j = 0; j < 10; ++j) z += lds_h1[r][j] * W2[j * H2N + c];
            v = fast_sigmoid(z);
        }
        lds_h2[r][c] = f2bf(v);
    }
    __syncthreads();

    // ---- layer 3 + tail via MFMA; A = W3-tile (rows = out cols), B = h2 (cols = out rows)
    // D: out row = rt*16 + (lane&15); out col-in-tile = (lane>>4)*4 + reg
    const int lane = t & 63, wid = t >> 6;
    const int lm = lane & 15, lg = lane >> 4;

    bf16x8 hfr[2][4];
    #pragma unroll
    for (int rt = 0; rt < 2; ++rt)
        #pragma unroll
        for (int ks = 0; ks < 4; ++ks)
            hfr[rt][ks] = *reinterpret_cast<const bf16x8*>(&lds_h2[rt * 16 + lm][ks * 32 + lg * 8]);

    #define LOADFRAG(dst, tile) do {                                              \
        const unsigned short* bp_ = w3f + ((size_t)((tile) * 4) * 64 + lane) * 8; \
        _Pragma("unroll")                                                         \
        for (int ks_ = 0; ks_ < 4; ++ks_)                                         \
            dst[ks_] = *reinterpret_cast<const bf16x8*>(bp_ + (size_t)ks_ * 512); \
    } while(0)

    for (int p = 0; p < NPANEL; ++p){
        const int tb = p * 16;
        const int te = (tb + 16 < NTILE) ? tb + 16 : NTILE;

        // -------- compute this panel's tiles (wave-strided, 1-deep frag prefetch)
        bf16x8 c1[4], c2[4], n1[4], n2[4];
        const int t0 = tb + wid;
        if (t0 < te){
            LOADFRAG(c1, t0);
            if (t0 >= T1OFF) LOADFRAG(c2, t0 + 61);
        }
        for (int tt = t0; tt < te; tt += 4){
            const int tn = tt + 4;
            if (tn < te){
                LOADFRAG(n1, tn);
                if (tn >= T1OFF) LOADFRAG(n2, tn + 61);
            }

            const int pc = (tt - tb) * 16 + lg * 4;      // panel col base
            if (tt < T1OFF){                              // main tile
                f32x4 a0 = {0,0,0,0}, a1 = {0,0,0,0};
                #pragma unroll
                for (int ks = 0; ks < 4; ++ks){
                    a0 = __builtin_amdgcn_mfma_f32_16x16x32_bf16(c1[ks], hfr[0][ks], a0, 0, 0, 0);
                    a1 = __builtin_amdgcn_mfma_f32_16x16x32_bf16(c1[ks], hfr[1][ks], a1, 0, 0, 0);
                }
                const f32x4 bv = *reinterpret_cast<const f32x4*>(b3f + tt * 16 + lg * 4);
                f32x4 v0, v1;
                #pragma unroll
                for (int r = 0; r < 4; ++r){
                    v0[r] = fast_sigmoid(a0[r] + bv[r]);
                    v1[r] = fast_sigmoid(a1[r] + bv[r]);
                }
                *reinterpret_cast<f32x4*>(&lds_p[lm][pc])      = v0;
                *reinterpret_cast<f32x4*>(&lds_p[16 + lm][pc]) = v1;
            } else {                                      // pair tile: lerp of two sides
                f32x4 a10 = {0,0,0,0}, a11 = {0,0,0,0};
                f32x4 a20 = {0,0,0,0}, a21 = {0,0,0,0};
                #pragma unroll
                for (int ks = 0; ks < 4; ++ks){
                    a10 = __builtin_amdgcn_mfma_f32_16x16x32_bf16(c1[ks], hfr[0][ks], a10, 0, 0, 0);
                    a11 = __builtin_amdgcn_mfma_f32_16x16x32_bf16(c1[ks], hfr[1][ks], a11, 0, 0, 0);
                }
                #pragma unroll
                for (int ks = 0; ks < 4; ++ks){
                    a20 = __builtin_amdgcn_mfma_f32_16x16x32_bf16(c2[ks], hfr[0][ks], a20, 0, 0, 0);
                    a21 = __builtin_amdgcn_mfma_f32_16x16x32_bf16(c2[ks], hfr[1][ks], a21, 0, 0, 0);
                }
                const f32x4 bv1 = *reinterpret_cast<const f32x4*>(b3f + tt * 16 + lg * 4);
                const f32x4 bv2 = *reinterpret_cast<const f32x4*>(b3f + (tt + 61) * 16 + lg * 4);
                const f32x4 wv  = *reinterpret_cast<const f32x4*>(pwf + (tt - T1OFF) * 16 + lg * 4);
                f32x4 v0, v1;
                #pragma unroll
                for (int r = 0; r < 4; ++r){
                    float u1 = fast_sigmoid(a10[r] + bv1[r]);
                    float u2 = fast_sigmoid(a20[r] + bv2[r]);
                    v0[r] = fmaf(wv[r], u1 - u2, u2);
                    u1 = fast_sigmoid(a11[r] + bv1[r]);
                    u2 = fast_sigmoid(a21[r] + bv2[r]);
                    v1[r] = fmaf(wv[r], u1 - u2, u2);
                }
                *reinterpret_cast<f32x4*>(&lds_p[lm][pc])      = v0;
                *reinterpret_cast<f32x4*>(&lds_p[16 + lm][pc]) = v1;
            }

            if (tn < te){
                #pragma unroll
                for (int ks = 0; ks < 4; ++ks){ c1[ks] = n1[ks]; c2[ks] = n2[ks]; }
            }
        }
        __syncthreads();

        // -------- dump panel: each wave writes 8 rows as 1-KB contiguous bursts
        const int vb = p * PANELW + lane * 4;   // lane's virtual col base
        int mode = 0, real = 0;                 // 0=skip, 1=full 16B, 2=single elem
        if (vb < 1224)                    { mode = 1; real = vb; }
        else if (vb >= 1232 && vb < 2200) { mode = 1; real = vb - 8; }
        else if (vb == 2200)              { mode = 2; real = vb - 8; }  // col 2192

        #pragma unroll
        for (int rr = 0; rr < 8; ++rr){
            const int row = wid * 8 + rr;
            f32x4 v = *reinterpret_cast<const f32x4*>(&lds_p[row][lane * 4]);
            const unsigned int off = (unsigned int)(row0 + row) * OUTW + real;
            if (mode == 1)      store16(out + off, v);
            else if (mode == 2) out[off] = v[0];
        }
        __syncthreads();
    }
    #undef LOADFRAG
}

extern "C" void kernel_launch(void* const* d_in, const int* in_sizes, int n_in,
                              void* d_out, int out_size, void* d_ws, size_t ws_size,
                              hipStream_t stream)
{
    const float* x   = (const float*)d_in[0];
    const float* W1  = (const float*)d_in[1];
    const float* b1  = (const float*)d_in[2];
    const float* W2  = (const float*)d_in[3];
    const float* b2  = (const float*)d_in[4];
    const float* W3  = (const float*)d_in[5];
    const float* b3  = (const float*)d_in[6];
    const float* wgt = (const float*)d_in[7];
    const int*   i1  = (const int*)d_in[8];
    const int*   i2  = (const int*)d_in[9];
    float* out = (float*)d_out;

    unsigned char* ws = (unsigned char*)d_ws;
    unsigned short* w3f = (unsigned short*)ws;                 // 199*4*64*8*2 = 815,104 B
    float*          b3f = (float*)(ws + 815104);               // 3184*4 = 12,736 B
    float*          pwf = (float*)(ws + 815104 + 12736);       // 976*4  =  3,904 B

    prep_kernel<<<NTOT, 256, 0, stream>>>(W3, b3, wgt, i1, i2, w3f, b3f, pwf);
    snn_kernel<<<NBLK, 256, 0, stream>>>(x, W1, b1, W2, b2, w3f, b3f, pwf, out);
}